// Round 14
// baseline (231.289 us; speedup 1.0000x reference)
//
#include <hip/hip_runtime.h>
#include <math.h>

typedef unsigned short u16;
typedef _Float16 f16;
typedef f16 f16x4 __attribute__((ext_vector_type(4)));
typedef f16 f16x8v __attribute__((ext_vector_type(8)));
typedef float f32x4 __attribute__((ext_vector_type(4)));

// ============================================================================
// R14: R13's K=32 register-chained weight-stream pipeline, re-tiled for more
// independent barrier domains:
//  - 256-thread blocks (4 waves, 4 elems) -> 4 blocks/CU = 4 independent
//    barrier domains (vs 2) covering each other's chunk-barrier stalls.
//  - 8 KB chunks (96-chunk stream, R12 map), ring-5 x 8 KB = 40 KB LDS,
//    prefetch depth 3, counted vmcnt(6) (2 loads/wave/chunk, 3 in flight).
//    Ring-5 depth-3 is race-free: slot (c+3)%5 = chunk c-2's slot, whose
//    reads completed before barrier c-1, which all staging waves have passed.
// Stream chunk map (8 KB each): wq 0-7, wk 8-15, wv 16-23, wfc1 24-39,
// w11 40-55, w12 56-71, w21 72-79, w22 80-95.
// f16 everywhere: v_cvt_f16_f32 is RNE (native bf16 cast truncates - round 6).
// ============================================================================

__device__ __forceinline__ float tanh_f(float x) {
  float e = __expf(2.f * x);
  return 1.f - 2.f / (e + 1.f);
}

// stage one 8KB chunk (source chunk si) into ring slot ds; 2 issues per wave
__device__ __forceinline__ void stage_chunk(const u16* __restrict__ wall, u16* wbuf,
                                            int si, int ds, int wid, int lane) {
  const u16* src = wall + (size_t)si * 4096;
  u16* dst = wbuf + ds * 4096;
#pragma unroll
  for (int j = 0; j < 2; ++j) {
    int seg = wid * 2 + j;  // 8 segments x 1 KB (4 waves x 2)
    __builtin_amdgcn_global_load_lds(
        (const __attribute__((address_space(1))) void*)(src + seg * 512 + lane * 8),
        (__attribute__((address_space(3))) void*)(dst + seg * 512), 16, 0, 0);
  }
}

__device__ __forceinline__ const u16* pipe_acq(const u16* __restrict__ wall, u16* wbuf,
                                               int c, int wid, int lane) {
  int nx = c + 3;
  if (nx >= 96) nx -= 96;  // dummy re-stage at tail (never read; drained at end)
  stage_chunk(wall, wbuf, nx, (c + 3) % 5, wid, lane);
  asm volatile("s_waitcnt vmcnt(6)" ::: "memory");  // own chunk-c loads complete
  __builtin_amdgcn_sched_barrier(0);
  __builtin_amdgcn_s_barrier();                     // ALL waves' c-segments visible
  __builtin_amdgcn_sched_barrier(0);
  return wbuf + (c % 5) * 4096;
}

// one 16-col output tile via K=32 MFMAs; local tile lt, PT = K/32 frags
template <int PT, bool SW>
__device__ __forceinline__ f32x4 tile_mm32(const u16* buf, int lt, const f16x8v* bfr,
                                           int lane) {
  f32x4 a = {};
#pragma unroll
  for (int p = 0; p < PT; ++p) {
    f16x8v w = *(const f16x8v*)(buf + (lt * PT + p) * 512 + (size_t)lane * 8);
    if constexpr (!SW)
      a = __builtin_amdgcn_mfma_f32_16x16x32_f16(w, bfr[p], a, 0, 0, 0);
    else
      a = __builtin_amdgcn_mfma_f32_16x16x32_f16(bfr[p], w, a, 0, 0, 0);
  }
  return a;
}

__global__ __launch_bounds__(256) void fused_kernel(
    const int* __restrict__ x, const float* __restrict__ node_emb,
    const u16* __restrict__ wall, const float* __restrict__ aux,
    const float* __restrict__ p1_b1, const float* __restrict__ p1_b2,
    const float* __restrict__ p1_lng, const float* __restrict__ p1_lnb,
    const float* __restrict__ p2_b1, const float* __restrict__ p2_b2,
    const float* __restrict__ lnc1_g, const float* __restrict__ lnc1_b,
    const float* __restrict__ lnc2_g, const float* __restrict__ lnc2_b,
    const float* __restrict__ Wcls, const float* __restrict__ bcls,
    float* __restrict__ out) {
  __shared__ __align__(16) u16 wbuf[20480];  // 5 x 8 KB ring
  const int lane = threadIdx.x & 63;
  const int wid = threadIdx.x >> 6;  // 0..3
  const int sr = lane & 15, g = lane >> 4;
  const int elem = blockIdx.x * 4 + wid;

  const int xi = x[elem * 16 + sr];
  const float npm = (xi != 0) ? 1.f : 0.f;

  // prologue: 3 chunks in flight; DMA overlaps the emb gather below
  stage_chunk(wall, wbuf, 0, 0, wid, lane);
  stage_chunk(wall, wbuf, 1, 1, wid, lane);
  stage_chunk(wall, wbuf, 2, 2, wid, lane);

  // ---- emb gather (f32, exact LN stats) -> f16 K=32 B-frags; row m = sr ----
  f16x8v ebf8[4];
  float mu, rs;
  {
    const float4* erow = (const float4*)(node_emb + (size_t)xi * 128 + g * 4);
    float su = 0.f, sq = 0.f;
#pragma unroll
    for (int t = 0; t < 8; ++t) {
      float4 v = erow[t * 4];
      su += v.x + v.y + v.z + v.w;
      sq += v.x * v.x + v.y * v.y + v.z * v.z + v.w * v.w;
      const int hb = (t & 1) * 4;
      ebf8[t >> 1][hb + 0] = (f16)v.x;
      ebf8[t >> 1][hb + 1] = (f16)v.y;
      ebf8[t >> 1][hb + 2] = (f16)v.z;
      ebf8[t >> 1][hb + 3] = (f16)v.w;
    }
    su += __shfl_xor(su, 16); su += __shfl_xor(su, 32);
    sq += __shfl_xor(sq, 16); sq += __shfl_xor(sq, 32);
    mu = su * (1.f / 128.f);
    rs = rsqrtf(sq * (1.f / 128.f) - mu * mu + 1e-5f);
  }

  int c = 0;

  // ---- wq (chunks 0-7, 2 tiles each): Q, LN folded via aux G/B ----
  f16x8v qf8[8];
#pragma unroll
  for (int cc = 0; cc < 8; ++cc) {
    const u16* buf = pipe_acq(wall, wbuf, c, wid, lane);
#pragma unroll
    for (int lt = 0; lt < 2; ++lt) {
      f32x4 a = tile_mm32<4, false>(buf, lt, ebf8, lane);
      const int T = cc * 2 + lt;
      float4 G4 = *(const float4*)(aux + T * 16 + g * 4);
      float4 B4 = *(const float4*)(aux + 256 + T * 16 + g * 4);
      const int hb = (T & 1) * 4;
#pragma unroll
      for (int i = 0; i < 4; ++i)
        qf8[T >> 1][hb + i] =
            (f16)(rs * (a[i] - mu * ((const float*)&G4)[i]) + ((const float*)&B4)[i]);
    }
    ++c;
  }

  // ---- wk (8-15): chunk cc = head cc; K tiles -> K=32 score MFMA + softmax ----
  f16x4 pb[8];
#pragma unroll
  for (int cc = 0; cc < 8; ++cc) {
    const u16* buf = pipe_acq(wall, wbuf, c, wid, lane);
    f16x8v kt8;
#pragma unroll
    for (int sub = 0; sub < 2; ++sub) {
      f32x4 a = tile_mm32<4, false>(buf, sub, ebf8, lane);
      const int T = cc * 2 + sub;
      float4 G4 = *(const float4*)(aux + 512 + T * 16 + g * 4);
      float4 B4 = *(const float4*)(aux + 512 + 256 + T * 16 + g * 4);
#pragma unroll
      for (int i = 0; i < 4; ++i)
        kt8[sub * 4 + i] =
            (f16)(rs * (a[i] - mu * ((const float*)&G4)[i]) + ((const float*)&B4)[i]);
    }
    f32x4 s4 = {};
    s4 = __builtin_amdgcn_mfma_f32_16x16x32_f16(kt8, qf8[cc], s4, 0, 0, 0);
    float e4[4], mx = -3.0e38f;
#pragma unroll
    for (int i = 0; i < 4; ++i) {
      float v = s4[i] * 0.17677669529663687f;  // 1/sqrt(32)
      if ((g * 4 + i) == sr) v = -3.0e38f;     // diagonal self-exclusion
      e4[i] = v;
      mx = fmaxf(mx, v);
    }
    mx = fmaxf(mx, __shfl_xor(mx, 16));
    mx = fmaxf(mx, __shfl_xor(mx, 32));
    float sm = 0.f;
#pragma unroll
    for (int i = 0; i < 4; ++i) {
      e4[i] = ((g * 4 + i) == sr) ? 0.f : __expf(e4[i] - mx);
      sm += e4[i];
    }
    sm += __shfl_xor(sm, 16);
    sm += __shfl_xor(sm, 32);
    float inv = 1.f / sm;
#pragma unroll
    for (int i = 0; i < 4; ++i) pb[cc][i] = (f16)(e4[i] * inv);
    ++c;
  }

  // ---- wv (16-23, swapped): V tile -> immediate PV (K=16) -> cf8 ----
  f16x8v cf8[8];
  {
    float mur[4], rsr[4];
#pragma unroll
    for (int i = 0; i < 4; ++i) {
      mur[i] = __shfl(mu, g * 4 + i);
      rsr[i] = __shfl(rs, g * 4 + i);
    }
#pragma unroll
    for (int cc = 0; cc < 8; ++cc) {
      const u16* buf = pipe_acq(wall, wbuf, c, wid, lane);
#pragma unroll
      for (int lt = 0; lt < 2; ++lt) {
        f32x4 a = tile_mm32<4, true>(buf, lt, ebf8, lane);
        const int T = cc * 2 + lt;
        float Gv = aux[1024 + T * 16 + sr];
        float Bv = aux[1024 + 256 + T * 16 + sr];
        f16x4 vt;
#pragma unroll
        for (int i = 0; i < 4; ++i) vt[i] = (f16)(rsr[i] * (a[i] - mur[i] * Gv) + Bv);
        f32x4 cacc = {};
        cacc = __builtin_amdgcn_mfma_f32_16x16x16f16(vt, pb[T >> 1], cacc, 0, 0, 0);
        const int hb = (T & 1) * 4;
#pragma unroll
        for (int i = 0; i < 4; ++i) cf8[T >> 1][hb + i] = (f16)cacc[i];
      }
      ++c;
    }
  }

  // ---- wfc1 (24-39, 1 tile each): dyn_in = (ctx @ Wfc1^T)*npm ----
  f16x8v dinf8[8];
#pragma unroll
  for (int T = 0; T < 16; ++T) {
    const u16* buf = pipe_acq(wall, wbuf, c, wid, lane);
    f32x4 a = tile_mm32<8, false>(buf, 0, cf8, lane);
    const int hb = (T & 1) * 4;
#pragma unroll
    for (int i = 0; i < 4; ++i) dinf8[T >> 1][hb + i] = (f16)(a[i] * npm);
    ++c;
  }

  // ---- w11 (40-55): h1 = tanh(din @ p1w1^T + b1) ----
  f16x8v h1f8[8];
#pragma unroll
  for (int T = 0; T < 16; ++T) {
    const u16* buf = pipe_acq(wall, wbuf, c, wid, lane);
    f32x4 a = tile_mm32<8, false>(buf, 0, dinf8, lane);
    float4 b = *(const float4*)(p1_b1 + T * 16 + g * 4);
    const int hb = (T & 1) * 4;
#pragma unroll
    for (int i = 0; i < 4; ++i)
      h1f8[T >> 1][hb + i] = (f16)tanh_f(a[i] + ((const float*)&b)[i]);
    ++c;
  }

  // ---- w12 (56-71): pre-LN h2 = gemm + b2 + dyn_in; f16 store + f32 stats ----
  f16x4 d1f[16];
  float s1 = 0.f, s2 = 0.f;
#pragma unroll
  for (int T = 0; T < 16; ++T) {
    const u16* buf = pipe_acq(wall, wbuf, c, wid, lane);
    f32x4 a = tile_mm32<8, false>(buf, 0, h1f8, lane);
    float4 b = *(const float4*)(p1_b2 + T * 16 + g * 4);
    const int hb = (T & 1) * 4;
#pragma unroll
    for (int i = 0; i < 4; ++i) {
      float v = a[i] + ((const float*)&b)[i] + (float)dinf8[T >> 1][hb + i];
      s1 += v;
      s2 += v * v;
      d1f[T][i] = (f16)v;
    }
    ++c;
  }
  // muA/rsA now (needed inside w22 loop)
  s1 += __shfl_xor(s1, 16); s1 += __shfl_xor(s1, 32);
  s2 += __shfl_xor(s2, 16); s2 += __shfl_xor(s2, 32);
  const float muA = s1 * (1.f / 256.f);
  const float rsA = rsqrtf(s2 * (1.f / 256.f) - muA * muA + 1e-5f);

  // ---- w21 (72-79, 2 tiles each): st1 = tanh(npm*(emb @ p2w1^T) + b1) ----
  f16x8v s1f8[8];
#pragma unroll
  for (int cc = 0; cc < 8; ++cc) {
    const u16* buf = pipe_acq(wall, wbuf, c, wid, lane);
#pragma unroll
    for (int lt = 0; lt < 2; ++lt) {
      f32x4 a = tile_mm32<4, false>(buf, lt, ebf8, lane);
      const int T = cc * 2 + lt;
      float4 b = *(const float4*)(p2_b1 + T * 16 + g * 4);
      const int hb = (T & 1) * 4;
#pragma unroll
      for (int i = 0; i < 4; ++i)
        s1f8[T >> 1][hb + i] = (f16)tanh_f(npm * a[i] + ((const float*)&b)[i]);
    }
    ++c;
  }

  // ---- w22 (80-95): sta consumed IMMEDIATELY via moment accumulation ----
  float M_puu = 0.f, M_qvv = 0.f, M_pquv = 0.f;
  float M_pug = 0.f, M_ppu = 0.f, M_pqu = 0.f;
  float M_qvg = 0.f, M_pqv = 0.f, M_qqv = 0.f;
  float t1 = 0.f, t2 = 0.f, v1 = 0.f, v2 = 0.f;
#pragma unroll
  for (int T = 0; T < 16; ++T) {
    const u16* buf = pipe_acq(wall, wbuf, c, wid, lane);
    f32x4 av = tile_mm32<8, false>(buf, 0, s1f8, lane);
    float4 b2 = *(const float4*)(p2_b2 + T * 16 + g * 4);
    float4 lg = *(const float4*)(p1_lng + T * 16 + g * 4);
    float4 lb = *(const float4*)(p1_lnb + T * 16 + g * 4);
    float4 wc = *(const float4*)(Wcls + T * 16 + g * 4);
    float4 pg4 = *(const float4*)(lnc1_g + T * 16 + g * 4);
    float4 qg4 = *(const float4*)(lnc2_g + T * 16 + g * 4);
    float4 eb4 = *(const float4*)(lnc1_b + T * 16 + g * 4);
    float4 fb4 = *(const float4*)(lnc2_b + T * 16 + g * 4);
#pragma unroll
    for (int i = 0; i < 4; ++i) {
      float v = (av[i] + ((const float*)&b2)[i]) * npm;             // sta
      float u = (((float)d1f[T][i] - muA) * rsA * ((const float*)&lg)[i] +
                 ((const float*)&lb)[i]) * npm;                     // dyn
      t1 += u; t2 += u * u; v1 += v; v2 += v * v;
      float gc = ((const float*)&eb4)[i] - ((const float*)&fb4)[i];
      float pu = ((const float*)&pg4)[i] * u;
      float qv = ((const float*)&qg4)[i] * v;
      float wpu = ((const float*)&wc)[i] * pu;
      float wqv = ((const float*)&wc)[i] * qv;
      M_puu = fmaf(wpu, pu, M_puu);
      M_qvv = fmaf(wqv, qv, M_qvv);
      M_pquv = fmaf(wpu, qv, M_pquv);
      M_pug = fmaf(wpu, gc, M_pug);
      M_ppu = fmaf(wpu, ((const float*)&pg4)[i], M_ppu);
      M_pqu = fmaf(wpu, ((const float*)&qg4)[i], M_pqu);
      M_qvg = fmaf(wqv, gc, M_qvg);
      M_pqv = fmaf(wqv, ((const float*)&pg4)[i], M_pqv);
      M_qqv = fmaf(wqv, ((const float*)&qg4)[i], M_qqv);
    }
    ++c;
  }
  asm volatile("s_waitcnt vmcnt(0)" ::: "memory");  // drain tail dummy stages

  // ---- reduce the 13 per-row accumulators over the 4 g-groups ----
#define RED2(z) z += __shfl_xor(z, 16); z += __shfl_xor(z, 32);
  RED2(t1) RED2(t2) RED2(v1) RED2(v2)
  RED2(M_puu) RED2(M_qvv) RED2(M_pquv)
  RED2(M_pug) RED2(M_ppu) RED2(M_pqu)
  RED2(M_qvg) RED2(M_pqv) RED2(M_qqv)
#undef RED2
  const float muD = t1 * (1.f / 256.f);
  const float aD = rsqrtf(t2 * (1.f / 256.f) - muD * muD + 1e-5f);
  const float muS = v1 * (1.f / 256.f);
  const float bS = rsqrtf(v2 * (1.f / 256.f) - muS * muS + 1e-5f);
  const float* s6 = aux + 1536;  // Mgg, Mpg, Mqg, Mpp, Mqq, Mpq
  float logit = aD * aD * M_puu + bS * bS * M_qvv - 2.f * aD * bS * M_pquv
      + 2.f * aD * (M_pug - aD * muD * M_ppu + bS * muS * M_pqu)
      - 2.f * bS * (M_qvg - aD * muD * M_pqv + bS * muS * M_qqv)
      + s6[0] - 2.f * aD * muD * s6[1] + 2.f * bS * muS * s6[2]
      + aD * aD * muD * muD * s6[3] + bS * bS * muS * muS * s6[4]
      - 2.f * aD * bS * muD * muS * s6[5]
      + bcls[0];
  float prob = npm / (1.f + __expf(-logit));
  float ns = npm;
#pragma unroll
  for (int o = 1; o < 16; o <<= 1) {
    prob += __shfl_xor(prob, o);
    ns += __shfl_xor(ns, o);
  }
  if (lane == 0) out[elem] = prob / ns;
}

// ---- prep: fp32 weights -> f16 PAIR-INTERLEAVED fragment packing (as R12) ----
// block blk = (n>>4)*(K>>4) + (k>>4); lane l = ((k>>2)&3)*16 + (n&15)
// u16 idx = (blk>>1)*512 + l*8 + (blk&1)*4 + (k&3)
// (pairs of adjacent k-16-tiles = one K=32 fragment per 16B lane read)
__global__ void prep_all(const float* __restrict__ Wq, const float* __restrict__ Wk,
                         const float* __restrict__ Wv, const float* __restrict__ Wfc1,
                         const float* __restrict__ p1w1, const float* __restrict__ p1w2,
                         const float* __restrict__ p2w1, const float* __restrict__ p2w2,
                         const float* __restrict__ g1, const float* __restrict__ b1,
                         const float* __restrict__ g2, const float* __restrict__ b2,
                         const float* __restrict__ g3, const float* __restrict__ b3,
                         const float* __restrict__ c1g, const float* __restrict__ c1b,
                         const float* __restrict__ c2g, const float* __restrict__ c2b,
                         const float* __restrict__ Wc,
                         u16* __restrict__ ws, float* __restrict__ aux) {
  int bx = blockIdx.x, t = threadIdx.x;
  if (bx == 1539) {  // classifier constant scalars
    if (t == 0) {
      float mgg = 0.f, mpg = 0.f, mqg = 0.f, mpp = 0.f, mqq = 0.f, mpq = 0.f;
      for (int cx = 0; cx < 256; ++cx) {
        float W = Wc[cx], p = c1g[cx], q = c2g[cx], gg = c1b[cx] - c2b[cx];
        mgg += W * gg * gg; mpg += W * p * gg; mqg += W * q * gg;
        mpp += W * p * p; mqq += W * q * q; mpq += W * p * q;
      }
      aux[1536] = mgg; aux[1537] = mpg; aux[1538] = mqg;
      aux[1539] = mpp; aux[1540] = mqq; aux[1541] = mpq;
    }
    return;
  }
  if (bx >= 1536) {
    int m = bx - 1536;
    const float* W = (m == 0) ? Wq : (m == 1) ? Wk : Wv;
    const float* gg = (m == 0) ? g1 : (m == 1) ? g2 : g3;
    const float* bb = (m == 0) ? b1 : (m == 1) ? b2 : b3;
    float G = 0.f, Bv = 0.f;
    for (int k = 0; k < 128; ++k) {
      float w = W[t * 128 + k];
      G += w * gg[k];
      Bv += w * bb[k];
    }
    aux[m * 512 + t] = G;
    aux[m * 512 + 256 + t] = Bv;
    return;
  }
  const float* src;
  u16* dst;
  const float* sc = nullptr;
  int base, K;
  if (bx < 128) {
    src = Wq; dst = ws; sc = g1; base = bx; K = 128;
  } else if (bx < 256) {
    src = Wk; dst = ws + 32768; sc = g2; base = bx - 128; K = 128;
  } else if (bx < 384) {
    src = Wv; dst = ws + 65536; sc = g3; base = bx - 256; K = 128;
  } else if (bx < 640) {
    src = Wfc1; dst = ws + 98304; base = bx - 384; K = 256;
  } else if (bx < 896) {
    src = p1w1; dst = ws + 163840; base = bx - 640; K = 256;
  } else if (bx < 1152) {
    src = p1w2; dst = ws + 229376; base = bx - 896; K = 256;
  } else if (bx < 1280) {
    src = p2w1; dst = ws + 294912; base = bx - 1152; K = 128;
  } else {
    src = p2w2; dst = ws + 327680; base = bx - 1280; K = 256;
  }
  int i = base * 256 + t;
  int n, k;
  if (K == 128) {
    n = i >> 7; k = i & 127;
  } else {
    n = i >> 8; k = i & 255;
  }
  float v = src[i];
  if (sc) v *= sc[k];
  int blk = (n >> 4) * (K >> 4) + (k >> 4);
  int l = (((k >> 2) & 3) << 4) + (n & 15);
  int di = ((blk >> 1) << 9) + (l << 3) + ((blk & 1) << 2) + (k & 3);
  dst[di] = __builtin_bit_cast(u16, (f16)v);
}

extern "C" void kernel_launch(void* const* d_in, const int* in_sizes, int n_in,
                              void* d_out, int out_size, void* d_ws, size_t ws_size,
                              hipStream_t stream) {
  const int* x = (const int*)d_in[0];
  const float* node_emb = (const float*)d_in[1];
  const float* ln1_g = (const float*)d_in[2];
  const float* ln1_b = (const float*)d_in[3];
  const float* ln2_g = (const float*)d_in[4];
  const float* ln2_b = (const float*)d_in[5];
  const float* ln3_g = (const float*)d_in[6];
  const float* ln3_b = (const float*)d_in[7];
  const float* Wq = (const float*)d_in[8];
  const float* Wk = (const float*)d_in[9];
  const float* Wv = (const float*)d_in[10];
  const float* Wfc1 = (const float*)d_in[11];
  const float* p1_w1 = (const float*)d_in[12];
  const float* p1_b1 = (const float*)d_in[13];
  const float* p1_w2 = (const float*)d_in[14];
  const float* p1_b2 = (const float*)d_in[15];
  const float* p1_lng = (const float*)d_in[16];
  const float* p1_lnb = (const float*)d_in[17];
  const float* p2_w1 = (const float*)d_in[18];
  const float* p2_b1 = (const float*)d_in[19];
  const float* p2_w2 = (const float*)d_in[20];
  const float* p2_b2 = (const float*)d_in[21];
  const float* lnc1_g = (const float*)d_in[22];
  const float* lnc1_b = (const float*)d_in[23];
  const float* lnc2_g = (const float*)d_in[24];
  const float* lnc2_b = (const float*)d_in[25];
  const float* Wcls = (const float*)d_in[26];
  const float* bcls = (const float*)d_in[27];

  u16* ws = (u16*)d_ws;
  float* aux = (float*)(ws + 393216);

  prep_all<<<1540, 256, 0, stream>>>(Wq, Wk, Wv, Wfc1, p1_w1, p1_w2, p2_w1, p2_w2, ln1_g, ln1_b,
                                     ln2_g, ln2_b, ln3_g, ln3_b, lnc1_g, lnc1_b, lnc2_g, lnc2_b,
                                     Wcls, ws, aux);

  const int B = in_sizes[0] / 16;
  fused_kernel<<<B / 4, 256, 0, stream>>>(
      x, node_emb, ws, aux, p1_b1, p1_b2, p1_lng, p1_lnb, p2_b1, p2_b2, lnc1_g, lnc1_b, lnc2_g,
      lnc2_b, Wcls, bcls, (float*)d_out);
}

// Round 15
// 213.696 us; speedup vs baseline: 1.0823x; 1.0823x over previous
//
#include <hip/hip_runtime.h>
#include <math.h>

typedef unsigned short u16;
typedef _Float16 f16;
typedef f16 f16x4 __attribute__((ext_vector_type(4)));
typedef f16 f16x8v __attribute__((ext_vector_type(8)));
typedef float f32x4 __attribute__((ext_vector_type(4)));

// ============================================================================
// R15: R13's K=32 weight-stream pipeline (512 thr, 8 elems/block, 16 KB
// chunks, 48-chunk stream) plus:
//  (a) s_setprio(1) around the per-chunk compute body (T5: waves in this
//      schedule are role-split staging/computing -> scheduler can favor
//      compute waves), setprio(0) during staging.
//  (b) prefetch depth 3, ring-5 x 16 KB = 80 KB LDS (2 blocks x 80 = 160 KB),
//      counted vmcnt(6) (2 loads/wave/chunk, 3 chunks in flight). Ring-5
//      depth-3 race-free: slot (c+3)%5 = chunk c-2's slot, whose reads
//      finished before barrier c-1, which this wave has passed.
// Stream chunk map (16 KB each): wq 0-3, wk 4-7, wv 8-11, wfc1 12-19,
// w11 20-27, w12 28-35, w21 36-39, w22 40-47.
// f16 everywhere: v_cvt_f16_f32 is RNE (native bf16 cast truncates - round 6).
// ============================================================================

__device__ __forceinline__ float tanh_f(float x) {
  float e = __expf(2.f * x);
  return 1.f - 2.f / (e + 1.f);
}

// stage one 16KB chunk (source chunk si) into ring slot ds; 2 issues per wave
__device__ __forceinline__ void stage_chunk(const u16* __restrict__ wall, u16* wbuf,
                                            int si, int ds, int wid, int lane) {
  const u16* src = wall + (size_t)si * 8192;
  u16* dst = wbuf + ds * 8192;
#pragma unroll
  for (int j = 0; j < 2; ++j) {
    __builtin_amdgcn_global_load_lds(
        (const __attribute__((address_space(1))) void*)(src + j * 4096 + wid * 512 + lane * 8),
        (__attribute__((address_space(3))) void*)(dst + j * 4096 + wid * 512), 16, 0, 0);
  }
}

__device__ __forceinline__ const u16* pipe_acq(const u16* __restrict__ wall, u16* wbuf,
                                               int c, int wid, int lane) {
  __builtin_amdgcn_s_setprio(0);  // staging/wait phase: deprioritize
  int nx = c + 3;
  if (nx >= 48) nx -= 48;  // dummy re-stage at tail (never read; drained at end)
  int slot = c + 3;
  while (slot >= 5) slot -= 5;
  stage_chunk(wall, wbuf, nx, slot, wid, lane);
  asm volatile("s_waitcnt vmcnt(6)" ::: "memory");  // own chunk-c loads complete
  __builtin_amdgcn_sched_barrier(0);
  __builtin_amdgcn_s_barrier();                     // ALL waves' c-segments visible
  __builtin_amdgcn_sched_barrier(0);
  __builtin_amdgcn_s_setprio(1);  // compute phase: prioritize
  int cs = c;
  while (cs >= 5) cs -= 5;
  return wbuf + cs * 8192;
}

// one 16-col output tile via K=32 MFMAs; local tile lt, PT = K/32 frags
template <int PT, bool SW>
__device__ __forceinline__ f32x4 tile_mm32(const u16* buf, int lt, const f16x8v* bfr,
                                           int lane) {
  f32x4 a = {};
#pragma unroll
  for (int p = 0; p < PT; ++p) {
    f16x8v w = *(const f16x8v*)(buf + (lt * PT + p) * 512 + (size_t)lane * 8);
    if constexpr (!SW)
      a = __builtin_amdgcn_mfma_f32_16x16x32_f16(w, bfr[p], a, 0, 0, 0);
    else
      a = __builtin_amdgcn_mfma_f32_16x16x32_f16(bfr[p], w, a, 0, 0, 0);
  }
  return a;
}

__global__ __launch_bounds__(512) void fused_kernel(
    const int* __restrict__ x, const float* __restrict__ node_emb,
    const u16* __restrict__ wall, const float* __restrict__ aux,
    const float* __restrict__ p1_b1, const float* __restrict__ p1_b2,
    const float* __restrict__ p1_lng, const float* __restrict__ p1_lnb,
    const float* __restrict__ p2_b1, const float* __restrict__ p2_b2,
    const float* __restrict__ lnc1_g, const float* __restrict__ lnc1_b,
    const float* __restrict__ lnc2_g, const float* __restrict__ lnc2_b,
    const float* __restrict__ Wcls, const float* __restrict__ bcls,
    float* __restrict__ out) {
  __shared__ __align__(16) u16 wbuf[40960];  // 5 x 16 KB ring
  const int lane = threadIdx.x & 63;
  const int wid = threadIdx.x >> 6;  // 0..7
  const int sr = lane & 15, g = lane >> 4;
  const int elem = blockIdx.x * 8 + wid;

  const int xi = x[elem * 16 + sr];
  const float npm = (xi != 0) ? 1.f : 0.f;

  // prologue: 3 chunks in flight; DMA overlaps the emb gather below
  stage_chunk(wall, wbuf, 0, 0, wid, lane);
  stage_chunk(wall, wbuf, 1, 1, wid, lane);
  stage_chunk(wall, wbuf, 2, 2, wid, lane);

  // ---- emb gather (f32, exact LN stats) -> f16 K=32 B-frags; row m = sr ----
  f16x8v ebf8[4];
  float mu, rs;
  {
    const float4* erow = (const float4*)(node_emb + (size_t)xi * 128 + g * 4);
    float su = 0.f, sq = 0.f;
#pragma unroll
    for (int t = 0; t < 8; ++t) {
      float4 v = erow[t * 4];
      su += v.x + v.y + v.z + v.w;
      sq += v.x * v.x + v.y * v.y + v.z * v.z + v.w * v.w;
      const int hb = (t & 1) * 4;
      ebf8[t >> 1][hb + 0] = (f16)v.x;
      ebf8[t >> 1][hb + 1] = (f16)v.y;
      ebf8[t >> 1][hb + 2] = (f16)v.z;
      ebf8[t >> 1][hb + 3] = (f16)v.w;
    }
    su += __shfl_xor(su, 16); su += __shfl_xor(su, 32);
    sq += __shfl_xor(sq, 16); sq += __shfl_xor(sq, 32);
    mu = su * (1.f / 128.f);
    rs = rsqrtf(sq * (1.f / 128.f) - mu * mu + 1e-5f);
  }

  int c = 0;

  // ---- wq (chunks 0-3, 4 tiles each): Q, LN folded via aux G/B ----
  f16x8v qf8[8];
#pragma unroll
  for (int cc = 0; cc < 4; ++cc) {
    const u16* buf = pipe_acq(wall, wbuf, c, wid, lane);
#pragma unroll
    for (int lt = 0; lt < 4; ++lt) {
      f32x4 a = tile_mm32<4, false>(buf, lt, ebf8, lane);
      const int T = cc * 4 + lt;
      float4 G4 = *(const float4*)(aux + T * 16 + g * 4);
      float4 B4 = *(const float4*)(aux + 256 + T * 16 + g * 4);
      const int hb = (T & 1) * 4;
#pragma unroll
      for (int i = 0; i < 4; ++i)
        qf8[T >> 1][hb + i] =
            (f16)(rs * (a[i] - mu * ((const float*)&G4)[i]) + ((const float*)&B4)[i]);
    }
    ++c;
  }

  // ---- wk (4-7): K tiles -> per-head K=32 score MFMA + softmax -> pb[h] ----
  f16x4 pb[8];
#pragma unroll
  for (int cc = 0; cc < 4; ++cc) {
    const u16* buf = pipe_acq(wall, wbuf, c, wid, lane);
#pragma unroll
    for (int hh = 0; hh < 2; ++hh) {
      f16x8v kt8;
#pragma unroll
      for (int sub = 0; sub < 2; ++sub) {
        f32x4 a = tile_mm32<4, false>(buf, hh * 2 + sub, ebf8, lane);
        const int T = cc * 4 + hh * 2 + sub;
        float4 G4 = *(const float4*)(aux + 512 + T * 16 + g * 4);
        float4 B4 = *(const float4*)(aux + 512 + 256 + T * 16 + g * 4);
#pragma unroll
        for (int i = 0; i < 4; ++i)
          kt8[sub * 4 + i] =
              (f16)(rs * (a[i] - mu * ((const float*)&G4)[i]) + ((const float*)&B4)[i]);
      }
      const int h = cc * 2 + hh;
      f32x4 s4 = {};
      s4 = __builtin_amdgcn_mfma_f32_16x16x32_f16(kt8, qf8[h], s4, 0, 0, 0);
      float e4[4], mx = -3.0e38f;
#pragma unroll
      for (int i = 0; i < 4; ++i) {
        float v = s4[i] * 0.17677669529663687f;  // 1/sqrt(32)
        if ((g * 4 + i) == sr) v = -3.0e38f;     // diagonal self-exclusion
        e4[i] = v;
        mx = fmaxf(mx, v);
      }
      mx = fmaxf(mx, __shfl_xor(mx, 16));
      mx = fmaxf(mx, __shfl_xor(mx, 32));
      float sm = 0.f;
#pragma unroll
      for (int i = 0; i < 4; ++i) {
        e4[i] = ((g * 4 + i) == sr) ? 0.f : __expf(e4[i] - mx);
        sm += e4[i];
      }
      sm += __shfl_xor(sm, 16);
      sm += __shfl_xor(sm, 32);
      float inv = 1.f / sm;
#pragma unroll
      for (int i = 0; i < 4; ++i) pb[h][i] = (f16)(e4[i] * inv);
    }
    ++c;
  }

  // ---- wv (8-11, swapped): V tile -> immediate PV (K=16) -> cf8 ----
  f16x8v cf8[8];
  {
    float mur[4], rsr[4];
#pragma unroll
    for (int i = 0; i < 4; ++i) {
      mur[i] = __shfl(mu, g * 4 + i);
      rsr[i] = __shfl(rs, g * 4 + i);
    }
#pragma unroll
    for (int cc = 0; cc < 4; ++cc) {
      const u16* buf = pipe_acq(wall, wbuf, c, wid, lane);
#pragma unroll
      for (int lt = 0; lt < 4; ++lt) {
        f32x4 a = tile_mm32<4, true>(buf, lt, ebf8, lane);
        const int T = cc * 4 + lt;
        float Gv = aux[1024 + T * 16 + sr];
        float Bv = aux[1024 + 256 + T * 16 + sr];
        f16x4 vt;
#pragma unroll
        for (int i = 0; i < 4; ++i) vt[i] = (f16)(rsr[i] * (a[i] - mur[i] * Gv) + Bv);
        f32x4 cacc = {};
        cacc = __builtin_amdgcn_mfma_f32_16x16x16f16(vt, pb[T >> 1], cacc, 0, 0, 0);
        const int hb = (T & 1) * 4;
#pragma unroll
        for (int i = 0; i < 4; ++i) cf8[T >> 1][hb + i] = (f16)cacc[i];
      }
      ++c;
    }
  }

  // ---- wfc1 (12-19, 2 tiles each): dyn_in = (ctx @ Wfc1^T)*npm ----
  f16x8v dinf8[8];
#pragma unroll
  for (int cc = 0; cc < 8; ++cc) {
    const u16* buf = pipe_acq(wall, wbuf, c, wid, lane);
#pragma unroll
    for (int lt = 0; lt < 2; ++lt) {
      f32x4 a = tile_mm32<8, false>(buf, lt, cf8, lane);
      const int T = cc * 2 + lt;
      const int hb = (T & 1) * 4;
#pragma unroll
      for (int i = 0; i < 4; ++i) dinf8[T >> 1][hb + i] = (f16)(a[i] * npm);
    }
    ++c;
  }

  // ---- w11 (20-27): h1 = tanh(din @ p1w1^T + b1) ----
  f16x8v h1f8[8];
#pragma unroll
  for (int cc = 0; cc < 8; ++cc) {
    const u16* buf = pipe_acq(wall, wbuf, c, wid, lane);
#pragma unroll
    for (int lt = 0; lt < 2; ++lt) {
      f32x4 a = tile_mm32<8, false>(buf, lt, dinf8, lane);
      const int T = cc * 2 + lt;
      float4 b = *(const float4*)(p1_b1 + T * 16 + g * 4);
      const int hb = (T & 1) * 4;
#pragma unroll
      for (int i = 0; i < 4; ++i)
        h1f8[T >> 1][hb + i] = (f16)tanh_f(a[i] + ((const float*)&b)[i]);
    }
    ++c;
  }

  // ---- w12 (28-35): pre-LN h2 = gemm + b2 + dyn_in; f16 store + f32 stats ----
  f16x4 d1f[16];
  float s1 = 0.f, s2 = 0.f;
#pragma unroll
  for (int cc = 0; cc < 8; ++cc) {
    const u16* buf = pipe_acq(wall, wbuf, c, wid, lane);
#pragma unroll
    for (int lt = 0; lt < 2; ++lt) {
      f32x4 a = tile_mm32<8, false>(buf, lt, h1f8, lane);
      const int T = cc * 2 + lt;
      float4 b = *(const float4*)(p1_b2 + T * 16 + g * 4);
      const int hb = (T & 1) * 4;
#pragma unroll
      for (int i = 0; i < 4; ++i) {
        float v = a[i] + ((const float*)&b)[i] + (float)dinf8[T >> 1][hb + i];
        s1 += v;
        s2 += v * v;
        d1f[T][i] = (f16)v;
      }
    }
    ++c;
  }
  // muA/rsA now (needed inside w22 loop)
  s1 += __shfl_xor(s1, 16); s1 += __shfl_xor(s1, 32);
  s2 += __shfl_xor(s2, 16); s2 += __shfl_xor(s2, 32);
  const float muA = s1 * (1.f / 256.f);
  const float rsA = rsqrtf(s2 * (1.f / 256.f) - muA * muA + 1e-5f);

  // ---- w21 (36-39): st1 = tanh(npm*(emb @ p2w1^T) + b1) ----
  f16x8v s1f8[8];
#pragma unroll
  for (int cc = 0; cc < 4; ++cc) {
    const u16* buf = pipe_acq(wall, wbuf, c, wid, lane);
#pragma unroll
    for (int lt = 0; lt < 4; ++lt) {
      f32x4 a = tile_mm32<4, false>(buf, lt, ebf8, lane);
      const int T = cc * 4 + lt;
      float4 b = *(const float4*)(p2_b1 + T * 16 + g * 4);
      const int hb = (T & 1) * 4;
#pragma unroll
      for (int i = 0; i < 4; ++i)
        s1f8[T >> 1][hb + i] = (f16)tanh_f(npm * a[i] + ((const float*)&b)[i]);
    }
    ++c;
  }

  // ---- w22 (40-47): sta consumed IMMEDIATELY via moment accumulation ----
  float M_puu = 0.f, M_qvv = 0.f, M_pquv = 0.f;
  float M_pug = 0.f, M_ppu = 0.f, M_pqu = 0.f;
  float M_qvg = 0.f, M_pqv = 0.f, M_qqv = 0.f;
  float t1 = 0.f, t2 = 0.f, v1 = 0.f, v2 = 0.f;
#pragma unroll
  for (int cc = 0; cc < 8; ++cc) {
    const u16* buf = pipe_acq(wall, wbuf, c, wid, lane);
#pragma unroll
    for (int lt = 0; lt < 2; ++lt) {
      f32x4 av = tile_mm32<8, false>(buf, lt, s1f8, lane);
      const int T = cc * 2 + lt;
      float4 b2 = *(const float4*)(p2_b2 + T * 16 + g * 4);
      float4 lg = *(const float4*)(p1_lng + T * 16 + g * 4);
      float4 lb = *(const float4*)(p1_lnb + T * 16 + g * 4);
      float4 wc = *(const float4*)(Wcls + T * 16 + g * 4);
      float4 pg4 = *(const float4*)(lnc1_g + T * 16 + g * 4);
      float4 qg4 = *(const float4*)(lnc2_g + T * 16 + g * 4);
      float4 eb4 = *(const float4*)(lnc1_b + T * 16 + g * 4);
      float4 fb4 = *(const float4*)(lnc2_b + T * 16 + g * 4);
#pragma unroll
      for (int i = 0; i < 4; ++i) {
        float v = (av[i] + ((const float*)&b2)[i]) * npm;             // sta
        float u = (((float)d1f[T][i] - muA) * rsA * ((const float*)&lg)[i] +
                   ((const float*)&lb)[i]) * npm;                     // dyn
        t1 += u; t2 += u * u; v1 += v; v2 += v * v;
        float gc = ((const float*)&eb4)[i] - ((const float*)&fb4)[i];
        float pu = ((const float*)&pg4)[i] * u;
        float qv = ((const float*)&qg4)[i] * v;
        float wpu = ((const float*)&wc)[i] * pu;
        float wqv = ((const float*)&wc)[i] * qv;
        M_puu = fmaf(wpu, pu, M_puu);
        M_qvv = fmaf(wqv, qv, M_qvv);
        M_pquv = fmaf(wpu, qv, M_pquv);
        M_pug = fmaf(wpu, gc, M_pug);
        M_ppu = fmaf(wpu, ((const float*)&pg4)[i], M_ppu);
        M_pqu = fmaf(wpu, ((const float*)&qg4)[i], M_pqu);
        M_qvg = fmaf(wqv, gc, M_qvg);
        M_pqv = fmaf(wqv, ((const float*)&pg4)[i], M_pqv);
        M_qqv = fmaf(wqv, ((const float*)&qg4)[i], M_qqv);
      }
    }
    ++c;
  }
  __builtin_amdgcn_s_setprio(0);
  asm volatile("s_waitcnt vmcnt(0)" ::: "memory");  // drain tail dummy stages

  // ---- reduce the 13 per-row accumulators over the 4 g-groups ----
#define RED2(z) z += __shfl_xor(z, 16); z += __shfl_xor(z, 32);
  RED2(t1) RED2(t2) RED2(v1) RED2(v2)
  RED2(M_puu) RED2(M_qvv) RED2(M_pquv)
  RED2(M_pug) RED2(M_ppu) RED2(M_pqu)
  RED2(M_qvg) RED2(M_pqv) RED2(M_qqv)
#undef RED2
  const float muD = t1 * (1.f / 256.f);
  const float aD = rsqrtf(t2 * (1.f / 256.f) - muD * muD + 1e-5f);
  const float muS = v1 * (1.f / 256.f);
  const float bS = rsqrtf(v2 * (1.f / 256.f) - muS * muS + 1e-5f);
  const float* s6 = aux + 1536;  // Mgg, Mpg, Mqg, Mpp, Mqq, Mpq
  float logit = aD * aD * M_puu + bS * bS * M_qvv - 2.f * aD * bS * M_pquv
      + 2.f * aD * (M_pug - aD * muD * M_ppu + bS * muS * M_pqu)
      - 2.f * bS * (M_qvg - aD * muD * M_pqv + bS * muS * M_qqv)
      + s6[0] - 2.f * aD * muD * s6[1] + 2.f * bS * muS * s6[2]
      + aD * aD * muD * muD * s6[3] + bS * bS * muS * muS * s6[4]
      - 2.f * aD * bS * muD * muS * s6[5]
      + bcls[0];
  float prob = npm / (1.f + __expf(-logit));
  float ns = npm;
#pragma unroll
  for (int o = 1; o < 16; o <<= 1) {
    prob += __shfl_xor(prob, o);
    ns += __shfl_xor(ns, o);
  }
  if (lane == 0) out[elem] = prob / ns;
}

// ---- prep: fp32 weights -> f16 PAIR-INTERLEAVED fragment packing (as R12) ----
// block blk = (n>>4)*(K>>4) + (k>>4); lane l = ((k>>2)&3)*16 + (n&15)
// u16 idx = (blk>>1)*512 + l*8 + (blk&1)*4 + (k&3)
// (pairs of adjacent k-16-tiles = one K=32 fragment per 16B lane read)
__global__ void prep_all(const float* __restrict__ Wq, const float* __restrict__ Wk,
                         const float* __restrict__ Wv, const float* __restrict__ Wfc1,
                         const float* __restrict__ p1w1, const float* __restrict__ p1w2,
                         const float* __restrict__ p2w1, const float* __restrict__ p2w2,
                         const float* __restrict__ g1, const float* __restrict__ b1,
                         const float* __restrict__ g2, const float* __restrict__ b2,
                         const float* __restrict__ g3, const float* __restrict__ b3,
                         const float* __restrict__ c1g, const float* __restrict__ c1b,
                         const float* __restrict__ c2g, const float* __restrict__ c2b,
                         const float* __restrict__ Wc,
                         u16* __restrict__ ws, float* __restrict__ aux) {
  int bx = blockIdx.x, t = threadIdx.x;
  if (bx == 1539) {  // classifier constant scalars
    if (t == 0) {
      float mgg = 0.f, mpg = 0.f, mqg = 0.f, mpp = 0.f, mqq = 0.f, mpq = 0.f;
      for (int cx = 0; cx < 256; ++cx) {
        float W = Wc[cx], p = c1g[cx], q = c2g[cx], gg = c1b[cx] - c2b[cx];
        mgg += W * gg * gg; mpg += W * p * gg; mqg += W * q * gg;
        mpp += W * p * p; mqq += W * q * q; mpq += W * p * q;
      }
      aux[1536] = mgg; aux[1537] = mpg; aux[1538] = mqg;
      aux[1539] = mpp; aux[1540] = mqq; aux[1541] = mpq;
    }
    return;
  }
  if (bx >= 1536) {
    int m = bx - 1536;
    const float* W = (m == 0) ? Wq : (m == 1) ? Wk : Wv;
    const float* gg = (m == 0) ? g1 : (m == 1) ? g2 : g3;
    const float* bb = (m == 0) ? b1 : (m == 1) ? b2 : b3;
    float G = 0.f, Bv = 0.f;
    for (int k = 0; k < 128; ++k) {
      float w = W[t * 128 + k];
      G += w * gg[k];
      Bv += w * bb[k];
    }
    aux[m * 512 + t] = G;
    aux[m * 512 + 256 + t] = Bv;
    return;
  }
  const float* src;
  u16* dst;
  const float* sc = nullptr;
  int base, K;
  if (bx < 128) {
    src = Wq; dst = ws; sc = g1; base = bx; K = 128;
  } else if (bx < 256) {
    src = Wk; dst = ws + 32768; sc = g2; base = bx - 128; K = 128;
  } else if (bx < 384) {
    src = Wv; dst = ws + 65536; sc = g3; base = bx - 256; K = 128;
  } else if (bx < 640) {
    src = Wfc1; dst = ws + 98304; base = bx - 384; K = 256;
  } else if (bx < 896) {
    src = p1w1; dst = ws + 163840; base = bx - 640; K = 256;
  } else if (bx < 1152) {
    src = p1w2; dst = ws + 229376; base = bx - 896; K = 256;
  } else if (bx < 1280) {
    src = p2w1; dst = ws + 294912; base = bx - 1152; K = 128;
  } else {
    src = p2w2; dst = ws + 327680; base = bx - 1280; K = 256;
  }
  int i = base * 256 + t;
  int n, k;
  if (K == 128) {
    n = i >> 7; k = i & 127;
  } else {
    n = i >> 8; k = i & 255;
  }
  float v = src[i];
  if (sc) v *= sc[k];
  int blk = (n >> 4) * (K >> 4) + (k >> 4);
  int l = (((k >> 2) & 3) << 4) + (n & 15);
  int di = ((blk >> 1) << 9) + (l << 3) + ((blk & 1) << 2) + (k & 3);
  dst[di] = __builtin_bit_cast(u16, (f16)v);
}

extern "C" void kernel_launch(void* const* d_in, const int* in_sizes, int n_in,
                              void* d_out, int out_size, void* d_ws, size_t ws_size,
                              hipStream_t stream) {
  const int* x = (const int*)d_in[0];
  const float* node_emb = (const float*)d_in[1];
  const float* ln1_g = (const float*)d_in[2];
  const float* ln1_b = (const float*)d_in[3];
  const float* ln2_g = (const float*)d_in[4];
  const float* ln2_b = (const float*)d_in[5];
  const float* ln3_g = (const float*)d_in[6];
  const float* ln3_b = (const float*)d_in[7];
  const float* Wq = (const float*)d_in[8];
  const float* Wk = (const float*)d_in[9];
  const float* Wv = (const float*)d_in[10];
  const float* Wfc1 = (const float*)d_in[11];
  const float* p1_w1 = (const float*)d_in[12];
  const float* p1_b1 = (const float*)d_in[13];
  const float* p1_w2 = (const float*)d_in[14];
  const float* p1_b2 = (const float*)d_in[15];
  const float* p1_lng = (const float*)d_in[16];
  const float* p1_lnb = (const float*)d_in[17];
  const float* p2_w1 = (const float*)d_in[18];
  const float* p2_b1 = (const float*)d_in[19];
  const float* p2_w2 = (const float*)d_in[20];
  const float* p2_b2 = (const float*)d_in[21];
  const float* lnc1_g = (const float*)d_in[22];
  const float* lnc1_b = (const float*)d_in[23];
  const float* lnc2_g = (const float*)d_in[24];
  const float* lnc2_b = (const float*)d_in[25];
  const float* Wcls = (const float*)d_in[26];
  const float* bcls = (const float*)d_in[27];

  u16* ws = (u16*)d_ws;
  float* aux = (float*)(ws + 393216);

  prep_all<<<1540, 256, 0, stream>>>(Wq, Wk, Wv, Wfc1, p1_w1, p1_w2, p2_w1, p2_w2, ln1_g, ln1_b,
                                     ln2_g, ln2_b, ln3_g, ln3_b, lnc1_g, lnc1_b, lnc2_g, lnc2_b,
                                     Wcls, ws, aux);

  const int B = in_sizes[0] / 16;
  fused_kernel<<<B / 8, 512, 0, stream>>>(
      x, node_emb, ws, aux, p1_b1, p1_b2, p1_lng, p1_lnb, p2_b1, p2_b2, lnc1_g, lnc1_b, lnc2_g,
      lnc2_b, Wcls, bcls, (float*)d_out);
}